// Round 4
// baseline (320.258 us; speedup 1.0000x reference)
//
#include <hip/hip_runtime.h>
#include <stdint.h>

#define N_NODES 500000
#define K_NB 16
#define F_IN 7
#define F_HID 40
#define F_OUT 3
#define NODE_FLOATS (K_NB * F_IN)   // 112 floats per node
#define NPW 16                      // nodes per wave-tile (500000 % 16 == 0)
#define WPB 4                       // waves per block
#define NPB (NPW * WPB)             // 64 nodes per block

typedef float v2f __attribute__((ext_vector_type(2)));

typedef __attribute__((address_space(3))) void lds_void_t;
typedef __attribute__((address_space(1))) const void glb_void_t;

// Prep: pack weights into d_ws as DUPLICATED pairs so the main kernel's
// v_pk_*_f32 ops take them straight from SGPR pairs (s_load, SMEM pipe)
// instead of per-h LDS broadcast reads (which were saturating the LDS pipe).
//   wtab  (float[40][16], ws+0):    h*16 + 2i{,+1} = W1[i][h] (i<7); [14..15]=b1[h]
//   w2tab (float[40][8],  ws+2560): h*8  + 2c{,+1} = W2[h][c] (c<3); [6..7]=0
__global__ void prep_kernel(const float* __restrict__ W1,
                            const float* __restrict__ b1,
                            const float* __restrict__ W2,
                            const float* __restrict__ b2,
                            float* __restrict__ ws)
{
    const int t = threadIdx.x;
    if (t < F_HID) {
        const int h = t;
        float* p = ws + h * 16;
        #pragma unroll
        for (int i = 0; i < F_IN; ++i) {
            const float w = W1[i * F_HID + h];
            p[2 * i + 0] = w;
            p[2 * i + 1] = w;
        }
        p[14] = b1[h];
        p[15] = b1[h];
    } else if (t < 2 * F_HID) {
        const int h = t - F_HID;
        float* p = ws + 40 * 16 + h * 8;
        #pragma unroll
        for (int c = 0; c < F_OUT; ++c) {
            const float w = W2[h * F_OUT + c];
            p[2 * c + 0] = w;
            p[2 * c + 1] = w;
        }
        p[6] = 0.0f;
        p[7] = 0.0f;
    }
}

// Main: wave stages 16 nodes coalesced via global_load_lds; 4 lanes/node,
// lane r owns k in {4r..4r+3} processed as two packed chains (4r,4r+1) and
// (4r+2,4r+3) -- vertical pairing (same feature j) keeps ReLU and the k-sum
// elementwise, so the whole h-loop runs on v_pk_*_f32 (2x fp32/instr).
// m-pairs {m[k][j], m[k+1][j]} are 7 LDS words apart -> ds_read2_b32,
// landing pre-packed in VGPR pairs. Layer 2 commuted past the k-mean.
__global__ __launch_bounds__(256) void aggre_kernel(
    const float* __restrict__ mailbox,
    const float* __restrict__ wtab,   // [40][16] duplicated-pair W1|b1
    const float* __restrict__ w2tab,  // [40][8]  duplicated-pair W2
    const float* __restrict__ b2,
    float* __restrict__ out)
{
    __shared__ __align__(16) float tile[WPB][NPW * NODE_FLOATS];  // 4 x 7168 B

    const int t = threadIdx.x;
    const int wave = t >> 6;
    const int lane = t & 63;
    const long tile0 = (long)blockIdx.x * NPB + (long)wave * NPW;
    if (tile0 >= N_NODES) return;   // wave-uniform; no barriers in this kernel

    // ---- stage 16 nodes (7168 B), coalesced, direct-to-LDS ----
    const float* gsrc = mailbox + (size_t)tile0 * NODE_FLOATS;
    #pragma unroll
    for (int j = 0; j < 7; ++j) {
        const float* g = gsrc + (size_t)(j * 64 + lane) * 4;
        __builtin_amdgcn_global_load_lds(
            (glb_void_t*)g,
            (lds_void_t*)&tile[wave][j * 256],
            16, 0, 0);
    }
    __builtin_amdgcn_s_waitcnt(0x0f70);  // vmcnt(0)

    // ---- pull this lane's 28 floats as 14 vertical pairs ----
    const int nloc = lane >> 2;
    const int r = lane & 3;
    const int base = nloc * NODE_FLOATS + r * 28;
    v2f mA[F_IN], mB[F_IN];
    #pragma unroll
    for (int j = 0; j < F_IN; ++j) {
        v2f a, b;
        a.x = tile[wave][base + j];          // k = 4r
        a.y = tile[wave][base + 7 + j];      // k = 4r+1   (ds_read2_b32)
        b.x = tile[wave][base + 14 + j];     // k = 4r+2
        b.y = tile[wave][base + 21 + j];     // k = 4r+3
        mA[j] = a;
        mB[j] = b;
    }

    const v2f* wt  = (const v2f*)wtab;   // [h*8 + j] j<7: W1 pair; [h*8+7]: b1 pair
    const v2f* w2t = (const v2f*)w2tab;  // [h*4 + c] c<3: W2 pair

    const v2f zero = {0.0f, 0.0f};
    v2f a0 = zero, a1 = zero, a2 = zero;

    #pragma unroll 4
    for (int h = 0; h < F_HID; ++h) {
        v2f accA = mA[0] * wt[h * 8 + 0];
        v2f accB = mB[0] * wt[h * 8 + 0];
        #pragma unroll
        for (int j = 1; j < F_IN; ++j) {
            accA = __builtin_elementwise_fma(mA[j], wt[h * 8 + j], accA);
            accB = __builtin_elementwise_fma(mB[j], wt[h * 8 + j], accB);
        }
        const v2f bp = wt[h * 8 + 7];
        accA = __builtin_elementwise_max(accA + bp, zero);
        accB = __builtin_elementwise_max(accB + bp, zero);
        const v2f sh = accA + accB;          // two k-partials per half
        a0 = __builtin_elementwise_fma(sh, w2t[h * 4 + 0], a0);
        a1 = __builtin_elementwise_fma(sh, w2t[h * 4 + 1], a1);
        a2 = __builtin_elementwise_fma(sh, w2t[h * 4 + 2], a2);
    }

    // ---- horizontal: combine packed halves, then quad-reduce over lanes ----
    float s0 = a0.x + a0.y;
    float s1 = a1.x + a1.y;
    float s2 = a2.x + a2.y;
    s0 += __shfl_xor(s0, 1); s0 += __shfl_xor(s0, 2);
    s1 += __shfl_xor(s1, 1); s1 += __shfl_xor(s1, 2);
    s2 += __shfl_xor(s2, 1); s2 += __shfl_xor(s2, 2);

    if (r < F_OUT) {
        const float val = (r == 0) ? s0 : ((r == 1) ? s1 : s2);
        out[(size_t)(tile0 + nloc) * F_OUT + r] =
            fmaf(val, 1.0f / (float)K_NB, b2[r]);
    }
}

extern "C" void kernel_launch(void* const* d_in, const int* in_sizes, int n_in,
                              void* d_out, int out_size, void* d_ws, size_t ws_size,
                              hipStream_t stream) {
    const float* mailbox = (const float*)d_in[0];
    const float* W1      = (const float*)d_in[1];
    const float* b1      = (const float*)d_in[2];
    const float* W2      = (const float*)d_in[3];
    const float* b2      = (const float*)d_in[4];
    float* ws  = (float*)d_ws;
    float* out = (float*)d_out;

    prep_kernel<<<1, 128, 0, stream>>>(W1, b1, W2, b2, ws);

    const float* wtab  = ws;            // 40*16 floats
    const float* w2tab = ws + 40 * 16;  // 40*8 floats
    const int blocks = (N_NODES + NPB - 1) / NPB;  // 7813
    aggre_kernel<<<blocks, 256, 0, stream>>>(mailbox, wtab, w2tab, b2, out);
}